// Round 1
// baseline (5174.692 us; speedup 1.0000x reference)
//
#include <hip/hip_runtime.h>
#include <math.h>

#define D_MODEL 1024
#define NHEADS  16
#define DK      64
#define SEQ     2048
#define BATCH   2

// ---------------------------------------------------------------------------
// Kernel 1: QKV projection.
// C[row, c] = dot(x[row, :], W_m[k, :])  where c in [0,3072), m = c/1024,
// k = c%1024 (= h*64 + dk). Block = 8 rows x 256 cols; x rows staged in LDS
// (uniform broadcast reads across the wave -> conflict-free), each thread
// streams one weight row with float4. Weights total 12 MB -> L2 resident.
// ---------------------------------------------------------------------------
__global__ __launch_bounds__(256) void qkv_proj_kernel(
    const float* __restrict__ x,
    const float* __restrict__ qw,
    const float* __restrict__ kw,
    const float* __restrict__ vw,
    float* __restrict__ Qo,   // [b, h, s, dk]
    float* __restrict__ Ko,
    float* __restrict__ Vo)
{
    __shared__ float xs[8][D_MODEL];   // 32 KB
    const int tid = threadIdx.x;
    const int r0  = blockIdx.y * 8;    // first of 8 rows (row = b*SEQ + s)

    // cooperative load of 8 x-rows: 8*1024/4 = 2048 float4, 256 threads
    const float4* xg  = (const float4*)(x + (size_t)r0 * D_MODEL);
    float4*       xls = (float4*)&xs[0][0];
    for (int i = tid; i < 2048; i += 256) xls[i] = xg[i];
    __syncthreads();

    const int c = blockIdx.x * 256 + tid;      // 0..3071
    const int m = c >> 10;                     // 0=Q, 1=K, 2=V
    const int k = c & 1023;                    // h*64 + dk
    const float* w = (m == 0 ? qw : (m == 1 ? kw : vw)) + (size_t)k * D_MODEL;
    const float4* w4 = (const float4*)w;

    float acc[8];
#pragma unroll
    for (int r = 0; r < 8; ++r) acc[r] = 0.f;

    for (int d4 = 0; d4 < D_MODEL / 4; ++d4) {
        float4 wv = w4[d4];
#pragma unroll
        for (int r = 0; r < 8; ++r) {
            float4 xv = ((const float4*)&xs[r][0])[d4];
            acc[r] += wv.x * xv.x + wv.y * xv.y + wv.z * xv.z + wv.w * xv.w;
        }
    }

    const int h = k >> 6, dki = k & 63;
    float* outb = (m == 0 ? Qo : (m == 1 ? Ko : Vo));
#pragma unroll
    for (int r = 0; r < 8; ++r) {
        int row = r0 + r;                 // b*SEQ + s
        int b = row >> 11, s = row & (SEQ - 1);
        outb[(((size_t)(b * NHEADS + h)) * SEQ + s) * DK + dki] = acc[r];
    }
}

// ---------------------------------------------------------------------------
// Kernel 2: causal attention, flash-style, one thread per query row.
// Block = 64 threads = one q-tile of 64 consecutive queries of one (b,h).
// All lanes walk the same K/V rows (uniform-address broadcast loads).
// Online softmax: rescale accumulator only when the running max moves.
// Output written as [b, s, h*64+dk] so the projection dot is contiguous.
// ---------------------------------------------------------------------------
__global__ __launch_bounds__(64) void attn_kernel(
    const float* __restrict__ Q,   // [b,h,s,dk]
    const float* __restrict__ K,
    const float* __restrict__ V,
    float* __restrict__ O)         // [b, s, 1024]
{
    const int bh  = blockIdx.x;          // 0..31  (b*16 + h)
    const int qt  = blockIdx.y;          // 0..31
    const int tid = threadIdx.x;
    const int q   = qt * 64 + tid;

    const float4* qptr = (const float4*)(Q + ((size_t)bh * SEQ + q) * DK);
    float4 qreg[16];
#pragma unroll
    for (int i = 0; i < 16; ++i) qreg[i] = qptr[i];

    float4 acc[16];
#pragma unroll
    for (int i = 0; i < 16; ++i) acc[i] = make_float4(0.f, 0.f, 0.f, 0.f);

    float mrow = -1e30f;
    float l    = 0.f;
    const int jmax = qt * 64 + 63;       // max query in this block
    const float scale = 0.125f;          // 1/sqrt(64)

    for (int j = 0; j <= jmax; ++j) {
        const float4* kr = (const float4*)(K + ((size_t)bh * SEQ + j) * DK);
        float sc = 0.f;
#pragma unroll
        for (int i = 0; i < 16; ++i) {
            float4 kv = kr[i];
            sc += qreg[i].x * kv.x + qreg[i].y * kv.y +
                  qreg[i].z * kv.z + qreg[i].w * kv.w;
        }
        sc *= scale;

        if (j <= q) {
            const float4* vr = (const float4*)(V + ((size_t)bh * SEQ + j) * DK);
            if (sc > mrow) {
                float f = __expf(mrow - sc);   // first iter: exp(-inf-ish)=0
                mrow = sc;
                l *= f;
#pragma unroll
                for (int i = 0; i < 16; ++i) {
                    acc[i].x *= f; acc[i].y *= f; acc[i].z *= f; acc[i].w *= f;
                }
            }
            float p = __expf(sc - mrow);
            l += p;
#pragma unroll
            for (int i = 0; i < 16; ++i) {
                float4 vv = vr[i];
                acc[i].x += p * vv.x; acc[i].y += p * vv.y;
                acc[i].z += p * vv.z; acc[i].w += p * vv.w;
            }
        }
    }

    const float inv = 1.f / l;
    const int b = bh >> 4, h = bh & 15;
    float4* o = (float4*)(O + ((size_t)(b * SEQ + q)) * D_MODEL + h * DK);
#pragma unroll
    for (int i = 0; i < 16; ++i) {
        float4 a = acc[i];
        o[i] = make_float4(a.x * inv, a.y * inv, a.z * inv, a.w * inv);
    }
}

// ---------------------------------------------------------------------------
// Kernel 3: output projection. out[row, d] = dot(A[row, :], Wo[d, :]).
// Same LDS structure as kernel 1. Writes are coalesced (thread -> col d).
// ---------------------------------------------------------------------------
__global__ __launch_bounds__(256) void out_proj_kernel(
    const float* __restrict__ A,    // [b, s, 1024]
    const float* __restrict__ Wo,   // [d, k]
    float* __restrict__ out)        // [b, s, d]
{
    __shared__ float as[8][D_MODEL];
    const int tid = threadIdx.x;
    const int r0  = blockIdx.y * 8;

    const float4* ag  = (const float4*)(A + (size_t)r0 * D_MODEL);
    float4*       als = (float4*)&as[0][0];
    for (int i = tid; i < 2048; i += 256) als[i] = ag[i];
    __syncthreads();

    const int d = blockIdx.x * 256 + tid;     // output column
    const float4* w4 = (const float4*)(Wo + (size_t)d * D_MODEL);

    float acc[8];
#pragma unroll
    for (int r = 0; r < 8; ++r) acc[r] = 0.f;

    for (int k4 = 0; k4 < D_MODEL / 4; ++k4) {
        float4 wv = w4[k4];
#pragma unroll
        for (int r = 0; r < 8; ++r) {
            float4 av = ((const float4*)&as[r][0])[k4];
            acc[r] += wv.x * av.x + wv.y * av.y + wv.z * av.z + wv.w * av.w;
        }
    }

#pragma unroll
    for (int r = 0; r < 8; ++r) {
        out[(size_t)(r0 + r) * D_MODEL + d] = acc[r];
    }
}

extern "C" void kernel_launch(void* const* d_in, const int* in_sizes, int n_in,
                              void* d_out, int out_size, void* d_ws, size_t ws_size,
                              hipStream_t stream) {
    const float* x  = (const float*)d_in[0];
    const float* qw = (const float*)d_in[1];
    const float* kw = (const float*)d_in[2];
    const float* vw = (const float*)d_in[3];
    const float* wo = (const float*)d_in[4];
    float* out = (float*)d_out;

    // workspace layout (fp32): Q,K,V each 4M elems, attn-out 4M elems = 64 MB
    float* ws = (float*)d_ws;
    float* Q  = ws;
    float* K  = ws + (size_t)4 * 1024 * 1024;
    float* V  = ws + (size_t)8 * 1024 * 1024;
    float* AO = ws + (size_t)12 * 1024 * 1024;

    dim3 g1(12, 512);            // 3072 cols / 256, 4096 rows / 8
    qkv_proj_kernel<<<g1, 256, 0, stream>>>(x, qw, kw, vw, Q, K, V);

    dim3 g2(32, 32);             // b*h, q-tiles of 64
    attn_kernel<<<g2, 64, 0, stream>>>(Q, K, V, AO);

    dim3 g3(4, 512);             // 1024 cols / 256, 4096 rows / 8
    out_proj_kernel<<<g3, 256, 0, stream>>>(AO, wo, out);
}

// Round 2
// 3140.860 us; speedup vs baseline: 1.6475x; 1.6475x over previous
//
#include <hip/hip_runtime.h>
#include <math.h>

#define D_MODEL 1024
#define NHEADS  16
#define DK      64
#define SEQ     2048
#define BATCH   2

// ---------------------------------------------------------------------------
// Kernel 1: QKV projection (unchanged this round; MFMA rewrite planned).
// ---------------------------------------------------------------------------
__global__ __launch_bounds__(256) void qkv_proj_kernel(
    const float* __restrict__ x,
    const float* __restrict__ qw,
    const float* __restrict__ kw,
    const float* __restrict__ vw,
    float* __restrict__ Qo,   // [b, h, s, dk]
    float* __restrict__ Ko,
    float* __restrict__ Vo)
{
    __shared__ float xs[8][D_MODEL];   // 32 KB
    const int tid = threadIdx.x;
    const int r0  = blockIdx.y * 8;    // first of 8 rows (row = b*SEQ + s)

    const float4* xg  = (const float4*)(x + (size_t)r0 * D_MODEL);
    float4*       xls = (float4*)&xs[0][0];
    for (int i = tid; i < 2048; i += 256) xls[i] = xg[i];
    __syncthreads();

    const int c = blockIdx.x * 256 + tid;      // 0..3071
    const int m = c >> 10;                     // 0=Q, 1=K, 2=V
    const int k = c & 1023;                    // h*64 + dk
    const float* w = (m == 0 ? qw : (m == 1 ? kw : vw)) + (size_t)k * D_MODEL;
    const float4* w4 = (const float4*)w;

    float acc[8];
#pragma unroll
    for (int r = 0; r < 8; ++r) acc[r] = 0.f;

    for (int d4 = 0; d4 < D_MODEL / 4; ++d4) {
        float4 wv = w4[d4];
#pragma unroll
        for (int r = 0; r < 8; ++r) {
            float4 xv = ((const float4*)&xs[r][0])[d4];
            acc[r] += wv.x * xv.x + wv.y * xv.y + wv.z * xv.z + wv.w * xv.w;
        }
    }

    const int h = k >> 6, dki = k & 63;
    float* outb = (m == 0 ? Qo : (m == 1 ? Ko : Vo));
#pragma unroll
    for (int r = 0; r < 8; ++r) {
        int row = r0 + r;                 // b*SEQ + s
        int b = row >> 11, s = row & (SEQ - 1);
        outb[(((size_t)(b * NHEADS + h)) * SEQ + s) * DK + dki] = acc[r];
    }
}

// ---------------------------------------------------------------------------
// Kernel 2: causal attention, flash-decoding split across 4 waves per block.
// Block = 256 threads = 4 waves; each wave owns the SAME 64 queries (one
// lane per query) but a distinct contiguous quarter of the key range
// [0, (qt+1)*64). Partial online-softmax states (m, l, acc) are merged
// through LDS with 4 sequential accumulate rounds. This gives 4x the
// wave-level parallelism of the 1-wave-per-tile version (latency hiding was
// the bottleneck: VALUBusy was 6.7%).
// ---------------------------------------------------------------------------
__global__ __launch_bounds__(256) void attn_kernel(
    const float* __restrict__ Q,   // [b,h,s,dk]
    const float* __restrict__ K,
    const float* __restrict__ V,
    float* __restrict__ O)         // [b, s, 1024]
{
    const int bh   = blockIdx.x;          // 0..31  (b*16 + h)
    const int qt   = 31 - blockIdx.y;     // long tiles launch first
    const int wave = threadIdx.x >> 6;    // 0..3
    const int lane = threadIdx.x & 63;
    const int q    = qt * 64 + lane;

    const int nkeys = (qt + 1) * 64;      // causal key count for this tile
    const int chunk = nkeys >> 2;         // multiple of 16
    const int lo    = wave * chunk;
    const int hi    = lo + chunk;

    const float4* qptr = (const float4*)(Q + ((size_t)bh * SEQ + q) * DK);
    float4 qreg[16];
#pragma unroll
    for (int i = 0; i < 16; ++i) qreg[i] = qptr[i];

    float4 acc[16];
#pragma unroll
    for (int i = 0; i < 16; ++i) acc[i] = make_float4(0.f, 0.f, 0.f, 0.f);

    float m = -1e30f;
    float l = 0.f;
    const float scale = 0.125f;           // 1/sqrt(64)

    for (int j = lo; j < hi; ++j) {
        const float4* kr = (const float4*)(K + ((size_t)bh * SEQ + j) * DK);
        float sc = 0.f;
#pragma unroll
        for (int i = 0; i < 16; ++i) {
            float4 kv = kr[i];
            sc += qreg[i].x * kv.x + qreg[i].y * kv.y +
                  qreg[i].z * kv.z + qreg[i].w * kv.w;
        }
        sc *= scale;

        if (j <= q) {
            const float4* vr = (const float4*)(V + ((size_t)bh * SEQ + j) * DK);
            if (sc > m) {
                float f = __expf(m - sc);
                m = sc;
                l *= f;
#pragma unroll
                for (int i = 0; i < 16; ++i) {
                    acc[i].x *= f; acc[i].y *= f; acc[i].z *= f; acc[i].w *= f;
                }
            }
            float p = __expf(sc - m);
            l += p;
#pragma unroll
            for (int i = 0; i < 16; ++i) {
                float4 vv = vr[i];
                acc[i].x += p * vv.x; acc[i].y += p * vv.y;
                acc[i].z += p * vv.z; acc[i].w += p * vv.w;
            }
        }
    }

    // ---- merge 4 partial states ------------------------------------------
    __shared__ float sm[4][64];
    __shared__ float sl[4][64];
    __shared__ float sacc[64][65];        // +1 pad: lane->bank conflict-free
    sm[wave][lane] = m;
    sl[wave][lane] = l;
    __syncthreads();

    float mstar = fmaxf(fmaxf(sm[0][lane], sm[1][lane]),
                        fmaxf(sm[2][lane], sm[3][lane]));
    float lstar = 0.f;
#pragma unroll
    for (int w = 0; w < 4; ++w)
        lstar += __expf(sm[w][lane] - mstar) * sl[w][lane];
    // per-wave scale; folds in the final 1/l normalization.
    // wave 0 always has l>0 (j=0 <= q), so lstar > 0.
    const float f = __expf(m - mstar) / lstar;

    for (int w = 0; w < 4; ++w) {
        if (wave == w) {
            float* row = &sacc[lane][0];
            if (w == 0) {
#pragma unroll
                for (int i = 0; i < 16; ++i) {
                    row[4*i+0] = acc[i].x * f; row[4*i+1] = acc[i].y * f;
                    row[4*i+2] = acc[i].z * f; row[4*i+3] = acc[i].w * f;
                }
            } else {
#pragma unroll
                for (int i = 0; i < 16; ++i) {
                    row[4*i+0] += acc[i].x * f; row[4*i+1] += acc[i].y * f;
                    row[4*i+2] += acc[i].z * f; row[4*i+3] += acc[i].w * f;
                }
            }
        }
        __syncthreads();
    }

    // ---- cooperative writeout: 256 threads x 16 floats -------------------
    const int orow  = threadIdx.x >> 2;   // query within tile
    const int opart = threadIdx.x & 3;    // 16-float segment
    const int b = bh >> 4, h = bh & 15;
    const int qg = qt * 64 + orow;
    float4* o4 = (float4*)(O + ((size_t)(b * SEQ + qg)) * D_MODEL
                             + h * DK + opart * 16);
#pragma unroll
    for (int i = 0; i < 4; ++i) {
        int c = opart * 16 + i * 4;
        o4[i] = make_float4(sacc[orow][c],   sacc[orow][c+1],
                            sacc[orow][c+2], sacc[orow][c+3]);
    }
}

// ---------------------------------------------------------------------------
// Kernel 3: output projection (unchanged this round).
// ---------------------------------------------------------------------------
__global__ __launch_bounds__(256) void out_proj_kernel(
    const float* __restrict__ A,    // [b, s, 1024]
    const float* __restrict__ Wo,   // [d, k]
    float* __restrict__ out)        // [b, s, d]
{
    __shared__ float as[8][D_MODEL];
    const int tid = threadIdx.x;
    const int r0  = blockIdx.y * 8;

    const float4* ag  = (const float4*)(A + (size_t)r0 * D_MODEL);
    float4*       als = (float4*)&as[0][0];
    for (int i = tid; i < 2048; i += 256) als[i] = ag[i];
    __syncthreads();

    const int d = blockIdx.x * 256 + tid;     // output column
    const float4* w4 = (const float4*)(Wo + (size_t)d * D_MODEL);

    float acc[8];
#pragma unroll
    for (int r = 0; r < 8; ++r) acc[r] = 0.f;

    for (int k4 = 0; k4 < D_MODEL / 4; ++k4) {
        float4 wv = w4[k4];
#pragma unroll
        for (int r = 0; r < 8; ++r) {
            float4 av = ((const float4*)&as[r][0])[k4];
            acc[r] += wv.x * av.x + wv.y * av.y + wv.z * av.z + wv.w * av.w;
        }
    }

#pragma unroll
    for (int r = 0; r < 8; ++r) {
        out[(size_t)(r0 + r) * D_MODEL + d] = acc[r];
    }
}

extern "C" void kernel_launch(void* const* d_in, const int* in_sizes, int n_in,
                              void* d_out, int out_size, void* d_ws, size_t ws_size,
                              hipStream_t stream) {
    const float* x  = (const float*)d_in[0];
    const float* qw = (const float*)d_in[1];
    const float* kw = (const float*)d_in[2];
    const float* vw = (const float*)d_in[3];
    const float* wo = (const float*)d_in[4];
    float* out = (float*)d_out;

    // workspace layout (fp32): Q,K,V each 4M elems, attn-out 4M elems = 64 MB
    float* ws = (float*)d_ws;
    float* Q  = ws;
    float* K  = ws + (size_t)4 * 1024 * 1024;
    float* V  = ws + (size_t)8 * 1024 * 1024;
    float* AO = ws + (size_t)12 * 1024 * 1024;

    dim3 g1(12, 512);            // 3072 cols / 256, 4096 rows / 8
    qkv_proj_kernel<<<g1, 256, 0, stream>>>(x, qw, kw, vw, Q, K, V);

    dim3 g2(32, 32);             // b*h, q-tiles of 64 (y reversed in-kernel)
    attn_kernel<<<g2, 256, 0, stream>>>(Q, K, V, AO);

    dim3 g3(4, 512);             // 1024 cols / 256, 4096 rows / 8
    out_proj_kernel<<<g3, 256, 0, stream>>>(AO, wo, out);
}

// Round 3
// 1341.630 us; speedup vs baseline: 3.8570x; 2.3411x over previous
//
#include <hip/hip_runtime.h>
#include <hip/hip_bf16.h>
#include <math.h>

#define D_MODEL 1024
#define NHEADS  16
#define DK      64
#define SEQ     2048
#define KDIM    1024

typedef __bf16 bf16x8 __attribute__((ext_vector_type(8)));
typedef float  f32x4  __attribute__((ext_vector_type(4)));

__device__ __forceinline__ void gload16(const void* g, void* l) {
    __builtin_amdgcn_global_load_lds(
        (const __attribute__((address_space(1))) void*)g,
        (__attribute__((address_space(3))) void*)l, 16, 0, 0);
}

__device__ __forceinline__ unsigned short f2bf(float f) {
    __hip_bfloat16 h = __float2bfloat16(f);
    return *(unsigned short*)&h;
}

// ---------------------------------------------------------------------------
// Kernel 0: cast x / qkv-weights / out-weights to bf16 workspace copies.
// float4 in -> 4x bf16 (ushort4) out. 2M float4s total.
// ---------------------------------------------------------------------------
__global__ __launch_bounds__(256) void cast_kernel(
    const float* __restrict__ x,
    const float* __restrict__ qw,
    const float* __restrict__ kw,
    const float* __restrict__ vw,
    const float* __restrict__ wo,
    unsigned short* __restrict__ xb,     // [4096*1024]
    unsigned short* __restrict__ wqkv,   // [3072*1024] (q rows, k rows, v rows)
    unsigned short* __restrict__ wob)    // [1024*1024]
{
    const size_t t = (size_t)blockIdx.x * 256 + threadIdx.x;  // float4 index
    const size_t X4 = 1048576;   // 4M elems / 4
    const size_t W4 = 262144;    // 1M elems / 4

    const float* src;
    unsigned short* dst;
    size_t o;
    if (t < X4)            { src = x;  dst = xb;             o = t; }
    else if (t < X4 + W4)  { src = qw; dst = wqkv;           o = t - X4; }
    else if (t < X4 + 2*W4){ src = kw; dst = wqkv + 1048576; o = t - X4 - W4; }
    else if (t < X4 + 3*W4){ src = vw; dst = wqkv + 2097152; o = t - X4 - 2*W4; }
    else                   { src = wo; dst = wob;            o = t - X4 - 3*W4; }

    float4 v = ((const float4*)src)[o];
    ushort4 r;
    r.x = f2bf(v.x); r.y = f2bf(v.y); r.z = f2bf(v.z); r.w = f2bf(v.w);
    ((ushort4*)dst)[o] = r;
}

// ---------------------------------------------------------------------------
// MFMA GEMM: C[M,N] = A[M,K] * B[N,K]^T, bf16 in, fp32 out. K = 1024.
// m97 structure: 128x128 tile, BK=32, 256 threads = 4 waves, each wave a
// 64x64 region = 4x4 tiles of 16x16x32 MFMA. global_load_lds width-16
// staging (wave-uniform LDS base + lane*16), 2-barrier K-loop.
// MODE 0: N=3072, scatter epilogue into Q/K/V [b,h,s,dk] fp32.
// MODE 1: N=1024, plain row-major store.
// ---------------------------------------------------------------------------
template<int MODE>
__global__ __launch_bounds__(256) void mfma_gemm(
    const unsigned short* __restrict__ A,   // [M,1024] bf16
    const unsigned short* __restrict__ B,   // [N,1024] bf16
    float* __restrict__ C0,
    float* __restrict__ C1,
    float* __restrict__ C2)
{
    __shared__ unsigned short As[128 * 32];   // 8 KB
    __shared__ unsigned short Bs[128 * 32];   // 8 KB

    const int tid  = threadIdx.x;
    const int wave = tid >> 6;
    const int lane = tid & 63;
    const int wr   = wave >> 1;        // 0..1
    const int wc   = wave & 1;         // 0..1
    const int quad = lane >> 4;        // 0..3
    const int l16  = lane & 15;

    const int rowBase = blockIdx.y * 128;
    const int colBase = blockIdx.x * 128;

    f32x4 acc[4][4];
    const f32x4 z = {0.f, 0.f, 0.f, 0.f};
#pragma unroll
    for (int i = 0; i < 4; ++i)
#pragma unroll
        for (int j = 0; j < 4; ++j) acc[i][j] = z;

    // staging: wave handles tile rows [wave*32, wave*32+32), 2 calls of 16
    // rows each. lane i covers row i>>2, k-chunk (i&3)*8 within the call.
    const int srow = lane >> 2;          // 0..15
    const int skof = (lane & 3) * 8;     // 0/8/16/24

    for (int k0 = 0; k0 < KDIM; k0 += 32) {
        __syncthreads();   // previous compute done before overwriting LDS

        const unsigned short* ga =
            A + (size_t)(rowBase + wave * 32) * KDIM + k0;
        gload16(ga + (size_t)srow * KDIM + skof,        &As[(wave*32)    * 32]);
        gload16(ga + (size_t)(16 + srow) * KDIM + skof, &As[(wave*32+16) * 32]);

        const unsigned short* gb =
            B + (size_t)(colBase + wave * 32) * KDIM + k0;
        gload16(gb + (size_t)srow * KDIM + skof,        &Bs[(wave*32)    * 32]);
        gload16(gb + (size_t)(16 + srow) * KDIM + skof, &Bs[(wave*32+16) * 32]);

        __syncthreads();   // drains vmcnt -> tiles visible

        bf16x8 af[4], bfr[4];
#pragma unroll
        for (int t = 0; t < 4; ++t)
            af[t] = *(const bf16x8*)&As[(wr*64 + t*16 + l16) * 32 + quad*8];
#pragma unroll
        for (int t = 0; t < 4; ++t)
            bfr[t] = *(const bf16x8*)&Bs[(wc*64 + t*16 + l16) * 32 + quad*8];

#pragma unroll
        for (int tr = 0; tr < 4; ++tr)
#pragma unroll
            for (int tc = 0; tc < 4; ++tc)
                acc[tr][tc] = __builtin_amdgcn_mfma_f32_16x16x32_bf16(
                    af[tr], bfr[tc], acc[tr][tc], 0, 0, 0);
    }

    // epilogue: C/D layout col = lane&15, row = quad*4 + reg
#pragma unroll
    for (int tr = 0; tr < 4; ++tr) {
#pragma unroll
        for (int tc = 0; tc < 4; ++tc) {
            const int grow0 = rowBase + wr*64 + tr*16 + quad*4;
            const int gcol  = colBase + wc*64 + tc*16 + l16;
            if (MODE == 0) {
                const int m  = gcol >> 10;
                const int kk = gcol & 1023;
                const int h  = kk >> 6, dk = kk & 63;
                float* dst = (m == 0 ? C0 : (m == 1 ? C1 : C2));
#pragma unroll
                for (int reg = 0; reg < 4; ++reg) {
                    const int r = grow0 + reg;
                    const int b = r >> 11, s = r & (SEQ - 1);
                    dst[((size_t)(b * NHEADS + h) * SEQ + s) * DK + dk] =
                        acc[tr][tc][reg];
                }
            } else {
#pragma unroll
                for (int reg = 0; reg < 4; ++reg)
                    C0[(size_t)(grow0 + reg) * D_MODEL + gcol] = acc[tr][tc][reg];
            }
        }
    }
}

// ---------------------------------------------------------------------------
// Kernel 2: causal attention, flash-decoding split across 4 waves per block
// (unchanged math; output now written as bf16 for the MFMA out-projection).
// ---------------------------------------------------------------------------
__global__ __launch_bounds__(256) void attn_kernel(
    const float* __restrict__ Q,   // [b,h,s,dk]
    const float* __restrict__ K,
    const float* __restrict__ V,
    unsigned short* __restrict__ O) // [b, s, 1024] bf16
{
    const int bh   = blockIdx.x;          // 0..31  (b*16 + h)
    const int qt   = 31 - blockIdx.y;     // long tiles launch first
    const int wave = threadIdx.x >> 6;    // 0..3
    const int lane = threadIdx.x & 63;
    const int q    = qt * 64 + lane;

    const int nkeys = (qt + 1) * 64;      // causal key count for this tile
    const int chunk = nkeys >> 2;         // multiple of 16
    const int lo    = wave * chunk;
    const int hi    = lo + chunk;

    const float4* qptr = (const float4*)(Q + ((size_t)bh * SEQ + q) * DK);
    float4 qreg[16];
#pragma unroll
    for (int i = 0; i < 16; ++i) qreg[i] = qptr[i];

    float4 acc[16];
#pragma unroll
    for (int i = 0; i < 16; ++i) acc[i] = make_float4(0.f, 0.f, 0.f, 0.f);

    float m = -1e30f;
    float l = 0.f;
    const float scale = 0.125f;           // 1/sqrt(64)

    for (int j = lo; j < hi; ++j) {
        const float4* kr = (const float4*)(K + ((size_t)bh * SEQ + j) * DK);
        float sc = 0.f;
#pragma unroll
        for (int i = 0; i < 16; ++i) {
            float4 kv = kr[i];
            sc += qreg[i].x * kv.x + qreg[i].y * kv.y +
                  qreg[i].z * kv.z + qreg[i].w * kv.w;
        }
        sc *= scale;

        if (j <= q) {
            const float4* vr = (const float4*)(V + ((size_t)bh * SEQ + j) * DK);
            if (sc > m) {
                float f = __expf(m - sc);
                m = sc;
                l *= f;
#pragma unroll
                for (int i = 0; i < 16; ++i) {
                    acc[i].x *= f; acc[i].y *= f; acc[i].z *= f; acc[i].w *= f;
                }
            }
            float p = __expf(sc - m);
            l += p;
#pragma unroll
            for (int i = 0; i < 16; ++i) {
                float4 vv = vr[i];
                acc[i].x += p * vv.x; acc[i].y += p * vv.y;
                acc[i].z += p * vv.z; acc[i].w += p * vv.w;
            }
        }
    }

    // ---- merge 4 partial states ------------------------------------------
    __shared__ float sm[4][64];
    __shared__ float sl[4][64];
    __shared__ float sacc[64][65];        // +1 pad
    sm[wave][lane] = m;
    sl[wave][lane] = l;
    __syncthreads();

    float mstar = fmaxf(fmaxf(sm[0][lane], sm[1][lane]),
                        fmaxf(sm[2][lane], sm[3][lane]));
    float lstar = 0.f;
#pragma unroll
    for (int w = 0; w < 4; ++w)
        lstar += __expf(sm[w][lane] - mstar) * sl[w][lane];
    const float f = __expf(m - mstar) / lstar;

    for (int w = 0; w < 4; ++w) {
        if (wave == w) {
            float* row = &sacc[lane][0];
            if (w == 0) {
#pragma unroll
                for (int i = 0; i < 16; ++i) {
                    row[4*i+0] = acc[i].x * f; row[4*i+1] = acc[i].y * f;
                    row[4*i+2] = acc[i].z * f; row[4*i+3] = acc[i].w * f;
                }
            } else {
#pragma unroll
                for (int i = 0; i < 16; ++i) {
                    row[4*i+0] += acc[i].x * f; row[4*i+1] += acc[i].y * f;
                    row[4*i+2] += acc[i].z * f; row[4*i+3] += acc[i].w * f;
                }
            }
        }
        __syncthreads();
    }

    // ---- cooperative writeout, bf16: 256 threads x 16 values -------------
    const int orow  = threadIdx.x >> 2;   // query within tile
    const int opart = threadIdx.x & 3;    // 16-value segment
    const int b = bh >> 4, h = bh & 15;
    const int qg = qt * 64 + orow;
    unsigned short* o = O + ((size_t)(b * SEQ + qg)) * D_MODEL
                          + h * DK + opart * 16;
    __align__(16) unsigned short tmp[16];
#pragma unroll
    for (int i = 0; i < 16; ++i)
        tmp[i] = f2bf(sacc[orow][opart * 16 + i]);
    ((uint4*)o)[0] = ((uint4*)tmp)[0];
    ((uint4*)o)[1] = ((uint4*)tmp)[1];
}

extern "C" void kernel_launch(void* const* d_in, const int* in_sizes, int n_in,
                              void* d_out, int out_size, void* d_ws, size_t ws_size,
                              hipStream_t stream) {
    const float* x  = (const float*)d_in[0];
    const float* qw = (const float*)d_in[1];
    const float* kw = (const float*)d_in[2];
    const float* vw = (const float*)d_in[3];
    const float* wo = (const float*)d_in[4];
    float* out = (float*)d_out;

    // workspace layout (64 MB total):
    //  [ 0,16) MB  Q fp32 [b,h,s,dk]
    //  [16,32) MB  K fp32
    //  [32,48) MB  V fp32
    //  [48,56) MB  xb bf16 [4096,1024]  -- reused as AO bf16 after QKV GEMM
    //  [56,62) MB  wqkv bf16 [3072,1024]
    //  [62,64) MB  wob  bf16 [1024,1024]
    char* ws = (char*)d_ws;
    float* Q = (float*)(ws);
    float* K = (float*)(ws + (size_t)16 * 1024 * 1024);
    float* V = (float*)(ws + (size_t)32 * 1024 * 1024);
    unsigned short* XB   = (unsigned short*)(ws + (size_t)48 * 1024 * 1024);
    unsigned short* AO   = XB;  // reuse: xb dead after QKV GEMM
    unsigned short* WQKV = (unsigned short*)(ws + (size_t)56 * 1024 * 1024);
    unsigned short* WOB  = (unsigned short*)(ws + (size_t)62 * 1024 * 1024);

    cast_kernel<<<8192, 256, 0, stream>>>(x, qw, kw, vw, wo, XB, WQKV, WOB);

    dim3 g1(24, 32);             // N=3072/128, M=4096/128
    mfma_gemm<0><<<g1, 256, 0, stream>>>(XB, WQKV, Q, K, V);

    dim3 g2(32, 32);             // b*h, q-tiles of 64 (y reversed in-kernel)
    attn_kernel<<<g2, 256, 0, stream>>>(Q, K, V, AO);

    dim3 g3(8, 32);              // N=1024/128, M=4096/128
    mfma_gemm<1><<<g3, 256, 0, stream>>>(AO, WOB, out, nullptr, nullptr);
}

// Round 4
// 185.349 us; speedup vs baseline: 27.9187x; 7.2384x over previous
//
#include <hip/hip_runtime.h>
#include <hip/hip_bf16.h>
#include <math.h>

#define D_MODEL 1024
#define NHEADS  16
#define DK      64
#define SEQ     2048
#define KDIM    1024

typedef __bf16 bf16x8 __attribute__((ext_vector_type(8)));
typedef float  f32x4  __attribute__((ext_vector_type(4)));

__device__ __forceinline__ void gload16(const void* g, void* l) {
    __builtin_amdgcn_global_load_lds(
        (const __attribute__((address_space(1))) void*)g,
        (__attribute__((address_space(3))) void*)l, 16, 0, 0);
}

__device__ __forceinline__ unsigned short f2bf(float f) {
    __hip_bfloat16 h = __float2bfloat16(f);
    return *(unsigned short*)&h;
}

// ---------------------------------------------------------------------------
// Kernel 0: cast x / qkv-weights / out-weights to bf16 workspace copies.
// ---------------------------------------------------------------------------
__global__ __launch_bounds__(256) void cast_kernel(
    const float* __restrict__ x,
    const float* __restrict__ qw,
    const float* __restrict__ kw,
    const float* __restrict__ vw,
    const float* __restrict__ wo,
    unsigned short* __restrict__ xb,     // [4096*1024]
    unsigned short* __restrict__ wqkv,   // [3072*1024]
    unsigned short* __restrict__ wob)    // [1024*1024]
{
    const size_t t = (size_t)blockIdx.x * 256 + threadIdx.x;  // float4 index
    const size_t X4 = 1048576;
    const size_t W4 = 262144;

    const float* src;
    unsigned short* dst;
    size_t o;
    if (t < X4)            { src = x;  dst = xb;             o = t; }
    else if (t < X4 + W4)  { src = qw; dst = wqkv;           o = t - X4; }
    else if (t < X4 + 2*W4){ src = kw; dst = wqkv + 1048576; o = t - X4 - W4; }
    else if (t < X4 + 3*W4){ src = vw; dst = wqkv + 2097152; o = t - X4 - 2*W4; }
    else                   { src = wo; dst = wob;            o = t - X4 - 3*W4; }

    float4 v = ((const float4*)src)[o];
    ushort4 r;
    r.x = f2bf(v.x); r.y = f2bf(v.y); r.z = f2bf(v.z); r.w = f2bf(v.w);
    ((ushort4*)dst)[o] = r;
}

// ---------------------------------------------------------------------------
// MFMA GEMM: C[M,N] = A[M,K]*B[N,K]^T, bf16 in. K=1024. m97 structure.
// MODE 0: N=3072 -> bf16 outputs: Q [bh,s,dk], K [bh,s,dk], V^T [bh,dk,s].
// MODE 1: N=1024 -> fp32 row-major C0.
// ---------------------------------------------------------------------------
template<int MODE>
__global__ __launch_bounds__(256) void mfma_gemm(
    const unsigned short* __restrict__ A,   // [M,1024] bf16
    const unsigned short* __restrict__ B,   // [N,1024] bf16
    float* __restrict__ C0,
    unsigned short* __restrict__ Qb,
    unsigned short* __restrict__ Kb,
    unsigned short* __restrict__ Vtb)
{
    __shared__ unsigned short As[128 * 32];
    __shared__ unsigned short Bs[128 * 32];

    const int tid  = threadIdx.x;
    const int wave = tid >> 6;
    const int lane = tid & 63;
    const int wr   = wave >> 1;
    const int wc   = wave & 1;
    const int quad = lane >> 4;
    const int l16  = lane & 15;

    const int rowBase = blockIdx.y * 128;
    const int colBase = blockIdx.x * 128;

    f32x4 acc[4][4];
    const f32x4 z = {0.f, 0.f, 0.f, 0.f};
#pragma unroll
    for (int i = 0; i < 4; ++i)
#pragma unroll
        for (int j = 0; j < 4; ++j) acc[i][j] = z;

    const int srow = lane >> 2;          // 0..15
    const int skof = (lane & 3) * 8;     // 0/8/16/24

    for (int k0 = 0; k0 < KDIM; k0 += 32) {
        __syncthreads();

        const unsigned short* ga =
            A + (size_t)(rowBase + wave * 32) * KDIM + k0;
        gload16(ga + (size_t)srow * KDIM + skof,        &As[(wave*32)    * 32]);
        gload16(ga + (size_t)(16 + srow) * KDIM + skof, &As[(wave*32+16) * 32]);

        const unsigned short* gb =
            B + (size_t)(colBase + wave * 32) * KDIM + k0;
        gload16(gb + (size_t)srow * KDIM + skof,        &Bs[(wave*32)    * 32]);
        gload16(gb + (size_t)(16 + srow) * KDIM + skof, &Bs[(wave*32+16) * 32]);

        __syncthreads();

        bf16x8 af[4], bfr[4];
#pragma unroll
        for (int t = 0; t < 4; ++t)
            af[t] = *(const bf16x8*)&As[(wr*64 + t*16 + l16) * 32 + quad*8];
#pragma unroll
        for (int t = 0; t < 4; ++t)
            bfr[t] = *(const bf16x8*)&Bs[(wc*64 + t*16 + l16) * 32 + quad*8];

#pragma unroll
        for (int tr = 0; tr < 4; ++tr)
#pragma unroll
            for (int tc = 0; tc < 4; ++tc)
                acc[tr][tc] = __builtin_amdgcn_mfma_f32_16x16x32_bf16(
                    af[tr], bfr[tc], acc[tr][tc], 0, 0, 0);
    }

    // C/D layout: col = lane&15, row = quad*4 + reg
#pragma unroll
    for (int tr = 0; tr < 4; ++tr) {
#pragma unroll
        for (int tc = 0; tc < 4; ++tc) {
            const int grow0 = rowBase + wr*64 + tr*16 + quad*4;
            const int gcol  = colBase + wc*64 + tc*16 + l16;
            if (MODE == 0) {
                const int m  = gcol >> 10;
                const int kk = gcol & 1023;
                const int h  = kk >> 6, dk = kk & 63;
                const int b  = grow0 >> 11, s0 = grow0 & (SEQ - 1);
                if (m == 2) {
                    // V^T [bh, dk, s]: 4 consecutive s -> packed 8B store
                    ushort4 pk;
                    pk.x = f2bf(acc[tr][tc][0]); pk.y = f2bf(acc[tr][tc][1]);
                    pk.z = f2bf(acc[tr][tc][2]); pk.w = f2bf(acc[tr][tc][3]);
                    *(ushort4*)(Vtb + ((size_t)(b*NHEADS + h)*DK + dk)*SEQ + s0) = pk;
                } else {
                    unsigned short* dst = (m == 0 ? Qb : Kb);
#pragma unroll
                    for (int reg = 0; reg < 4; ++reg)
                        dst[((size_t)(b*NHEADS + h)*SEQ + s0 + reg)*DK + dk] =
                            f2bf(acc[tr][tc][reg]);
                }
            } else {
#pragma unroll
                for (int reg = 0; reg < 4; ++reg)
                    C0[(size_t)(grow0 + reg) * D_MODEL + gcol] = acc[tr][tc][reg];
            }
        }
    }
}

// ---------------------------------------------------------------------------
// Kernel 2: MFMA flash attention (transposed formulation).
// Block = 4 waves, one (b,h), 64-query tile; wave w privately owns q rows
// [w*16, w*16+16). Per 64-key tile: stage K [64 keys][64 dk] and V^T
// [64 dk][64 keys] bf16 to LDS (global_load_lds w16, XOR chunk swizzle
// folded into the GLOBAL address since LDS dst is lane*16 fixed).
// Compute S^T = K·Q^T  (C-layout: col=l16=QUERY, row=quad*4+reg=key) so
// softmax stats are per-lane; P^T packs 4 keys per ds_write_b64; then
// O^T = V^T·P^T. Epilogue: packed ushort4 bf16 stores to AO [b,s,1024].
// ---------------------------------------------------------------------------
__global__ __launch_bounds__(256) void attn_mfma_kernel(
    const unsigned short* __restrict__ Qb,   // [bh, s, 64] bf16
    const unsigned short* __restrict__ Kb,   // [bh, s, 64] bf16
    const unsigned short* __restrict__ Vtb,  // [bh, 64, s] bf16
    unsigned short* __restrict__ O)          // [b, s, 1024] bf16
{
    __shared__ unsigned short Ks[64 * 64];       // 8 KB
    __shared__ unsigned short Vs[64 * 64];       // 8 KB
    __shared__ unsigned short Ps[4 * 16 * 64];   // 8 KB (per-wave 16x64)

    const int bh   = blockIdx.x;
    const int qt   = 31 - blockIdx.y;     // long (causal-heavy) tiles first
    const int wave = threadIdx.x >> 6;
    const int lane = threadIdx.x & 63;
    const int quad = lane >> 4;
    const int l16  = lane & 15;

    // Q fragment (B-operand of S^T = K·Q^T): row n = q = l16 of wave's strip
    const size_t qrow = (size_t)bh * SEQ + qt*64 + wave*16 + l16;
    bf16x8 aq0 = *(const bf16x8*)(Qb + qrow * DK + quad*8);
    bf16x8 aq1 = *(const bf16x8*)(Qb + qrow * DK + 32 + quad*8);

    f32x4 o_acc[4];
    const f32x4 z = {0.f, 0.f, 0.f, 0.f};
#pragma unroll
    for (int i = 0; i < 4; ++i) o_acc[i] = z;
    float mrow = -1e30f, lrow = 0.f;

    const int srow8  = lane >> 3;    // row within 8-row staging slab
    const int schunk = lane & 7;     // LDS 16B-chunk position
    const unsigned short* Kbase = Kb  + (size_t)bh * SEQ * DK;
    const unsigned short* Vbase = Vtb + (size_t)bh * DK * SEQ;
    const float scale = 0.125f;

    const int ntiles = qt + 1;
    for (int jt = 0; jt < ntiles; ++jt) {
        const int j0 = jt * 64;
        __syncthreads();   // all waves done with previous K/V tile
#pragma unroll
        for (int n = 0; n < 2; ++n) {
            const int r = wave*16 + n*8 + srow8;      // r & 7 == srow8
            gload16(Kbase + (size_t)(j0 + r) * DK + (schunk ^ srow8) * 8,
                    &Ks[(wave*16 + n*8) * 64]);
            gload16(Vbase + (size_t)r * SEQ + j0 + (schunk ^ srow8) * 8,
                    &Vs[(wave*16 + n*8) * 64]);
        }
        __syncthreads();   // vmcnt drained -> tiles visible

        // S^T = K·Q^T : A = K rows (m = key), B = Q rows (n = query)
        f32x4 st[4];
#pragma unroll
        for (int ct = 0; ct < 4; ++ct) {
            const int r = ct*16 + l16;               // key row
            bf16x8 k0 = *(const bf16x8*)&Ks[r*64 + ((quad     ^ (r&7)) * 8)];
            bf16x8 k1 = *(const bf16x8*)&Ks[r*64 + (((4+quad) ^ (r&7)) * 8)];
            f32x4 t = z;
            t = __builtin_amdgcn_mfma_f32_16x16x32_bf16(k0, aq0, t, 0, 0, 0);
            t = __builtin_amdgcn_mfma_f32_16x16x32_bf16(k1, aq1, t, 0, 0, 0);
            st[ct] = t;
        }

        // scale + causal mask (diagonal tile only): key_local <= q_local
        if (jt == qt) {
#pragma unroll
            for (int ct = 0; ct < 4; ++ct)
#pragma unroll
                for (int reg = 0; reg < 4; ++reg) {
                    const int kl = ct*16 + quad*4 + reg;
                    const int ql = wave*16 + l16;
                    st[ct][reg] = (kl <= ql) ? st[ct][reg] * scale : -1e30f;
                }
        } else {
#pragma unroll
            for (int ct = 0; ct < 4; ++ct)
#pragma unroll
                for (int reg = 0; reg < 4; ++reg) st[ct][reg] *= scale;
        }

        // per-lane stats (lane's 16 values all belong to query l16),
        // then combine across the 4 quads (lanes l16, l16+16, +32, +48)
        float mx = st[0][0];
#pragma unroll
        for (int ct = 0; ct < 4; ++ct)
#pragma unroll
            for (int reg = 0; reg < 4; ++reg) mx = fmaxf(mx, st[ct][reg]);
        mx = fmaxf(mx, __shfl_xor(mx, 16));
        mx = fmaxf(mx, __shfl_xor(mx, 32));

        const float mnew  = fmaxf(mrow, mx);
        const float alpha = __expf(mrow - mnew);
        mrow = mnew;

        float rs = 0.f;
#pragma unroll
        for (int ct = 0; ct < 4; ++ct)
#pragma unroll
            for (int reg = 0; reg < 4; ++reg) {
                float p = __expf(st[ct][reg] - mnew);
                st[ct][reg] = p;
                rs += p;
            }
        rs += __shfl_xor(rs, 16);
        rs += __shfl_xor(rs, 32);
        lrow = lrow * alpha + rs;
#pragma unroll
        for (int ot = 0; ot < 4; ++ot) {
            o_acc[ot][0] *= alpha; o_acc[ot][1] *= alpha;
            o_acc[ot][2] *= alpha; o_acc[ot][3] *= alpha;
        }

        // P^T -> LDS: row q=l16, 4 consecutive keys packed per b64 write;
        // 8B-granule XOR swizzle (granule g at position g ^ 2*(row&7))
        unsigned short* Pw = &Ps[wave * 1024];
#pragma unroll
        for (int ct = 0; ct < 4; ++ct) {
            ushort4 pk;
            pk.x = f2bf(st[ct][0]); pk.y = f2bf(st[ct][1]);
            pk.z = f2bf(st[ct][2]); pk.w = f2bf(st[ct][3]);
            const int g = (ct*4 + quad) ^ ((l16 & 7) << 1);
            *(ushort4*)(Pw + l16*64 + g*4) = pk;
        }

        // B-frags of P^T: row n=q=l16, chunk kk*4+quad (16B = 2 granules)
        bf16x8 bp0 = *(const bf16x8*)(Pw + l16*64 + ((quad     ^ (l16&7)) * 8));
        bf16x8 bp1 = *(const bf16x8*)(Pw + l16*64 + (((4+quad) ^ (l16&7)) * 8));

        // O^T += V^T · P^T  (A = V^T rows: m = dk)
#pragma unroll
        for (int ot = 0; ot < 4; ++ot) {
            const int r = ot*16 + l16;               // dk row
            bf16x8 v0 = *(const bf16x8*)&Vs[r*64 + ((quad     ^ (r&7)) * 8)];
            bf16x8 v1 = *(const bf16x8*)&Vs[r*64 + (((4+quad) ^ (r&7)) * 8)];
            o_acc[ot] = __builtin_amdgcn_mfma_f32_16x16x32_bf16(v0, bp0, o_acc[ot], 0, 0, 0);
            o_acc[ot] = __builtin_amdgcn_mfma_f32_16x16x32_bf16(v1, bp1, o_acc[ot], 0, 0, 0);
        }
    }

    // epilogue: lane owns query l16, dk = ot*16 + quad*4 + reg
    const float inv = 1.f / lrow;
    const int b = bh >> 4, h = bh & 15;
    const int sg = qt*64 + wave*16 + l16;
    unsigned short* orow = O + ((size_t)(b * SEQ + sg)) * D_MODEL + h * DK;
#pragma unroll
    for (int ot = 0; ot < 4; ++ot) {
        ushort4 pk;
        pk.x = f2bf(o_acc[ot][0] * inv); pk.y = f2bf(o_acc[ot][1] * inv);
        pk.z = f2bf(o_acc[ot][2] * inv); pk.w = f2bf(o_acc[ot][3] * inv);
        *(ushort4*)(orow + ot*16 + quad*4) = pk;
    }
}

extern "C" void kernel_launch(void* const* d_in, const int* in_sizes, int n_in,
                              void* d_out, int out_size, void* d_ws, size_t ws_size,
                              hipStream_t stream) {
    const float* x  = (const float*)d_in[0];
    const float* qw = (const float*)d_in[1];
    const float* kw = (const float*)d_in[2];
    const float* vw = (const float*)d_in[3];
    const float* wo = (const float*)d_in[4];
    float* out = (float*)d_out;

    // workspace (48 MB of the 64): all bf16
    //  [ 0, 8) Qb [bh,s,64]   [ 8,16) Kb   [16,24) Vt [bh,64,s]
    //  [24,32) AO [b,s,1024]  [32,40) XB   [40,46) WQKV  [46,48) WOB
    char* ws = (char*)d_ws;
    unsigned short* Qb   = (unsigned short*)(ws);
    unsigned short* Kb   = (unsigned short*)(ws + (size_t) 8*1024*1024);
    unsigned short* Vtb  = (unsigned short*)(ws + (size_t)16*1024*1024);
    unsigned short* AO   = (unsigned short*)(ws + (size_t)24*1024*1024);
    unsigned short* XB   = (unsigned short*)(ws + (size_t)32*1024*1024);
    unsigned short* WQKV = (unsigned short*)(ws + (size_t)40*1024*1024);
    unsigned short* WOB  = (unsigned short*)(ws + (size_t)46*1024*1024);

    cast_kernel<<<8192, 256, 0, stream>>>(x, qw, kw, vw, wo, XB, WQKV, WOB);

    dim3 g1(24, 32);             // N=3072/128, M=4096/128
    mfma_gemm<0><<<g1, 256, 0, stream>>>(XB, WQKV, nullptr, Qb, Kb, Vtb);

    dim3 g2(32, 32);             // bh, q-tiles (y reversed in-kernel)
    attn_mfma_kernel<<<g2, 256, 0, stream>>>(Qb, Kb, Vtb, AO);

    dim3 g3(8, 32);              // N=1024/128, M=4096/128
    mfma_gemm<1><<<g3, 256, 0, stream>>>(AO, WOB, out, nullptr, nullptr, nullptr);
}